// Round 2
// baseline (156280.896 us; speedup 1.0000x reference)
//
#include <hip/hip_runtime.h>
#include <math.h>

#define TT 8192
#define DD 128
#define HH 1024
#define RINGN 256          // ring slots (power of 2)
#define NA 64              // layer-0 workgroups
#define NB 128             // layer-1 workgroups
#define NC 16              // decoder workgroups
#define NWG (NA + NB + NC)

// d_ws layout (bytes):
//   [0)      a_flag u32[64]    (per-WG epoch: steps completed)
//   [512)    b_flag u32[128]
//   [1536)   c_flag u32[16]
//   [131072) h0_ring f32[RINGN][HH]
//   [131072 + RINGN*HH*4) h1_ring f32[RINGN][HH]

__device__ __forceinline__ unsigned ldrlx(const unsigned* p) {
  return __hip_atomic_load(p, __ATOMIC_RELAXED, __HIP_MEMORY_SCOPE_AGENT);
}
__device__ __forceinline__ void strel(unsigned* p, unsigned v) {
  __hip_atomic_store(p, v, __ATOMIC_RELEASE, __HIP_MEMORY_SCOPE_AGENT);
}
__device__ __forceinline__ void st_ring(float* p, float v) {
  __hip_atomic_store(p, v, __ATOMIC_RELAXED, __HIP_MEMORY_SCOPE_AGENT);
}
__device__ __forceinline__ float sigm(float x) { return 1.0f / (1.0f + expf(-x)); }
__device__ __forceinline__ float softplusf(float x) {
  return x > 0.0f ? x + log1pf(expf(-x)) : log1pf(expf(x));
}
__device__ __forceinline__ unsigned wave_min(unsigned m) {
  #pragma unroll
  for (int s = 32; s; s >>= 1) {
    unsigned o = (unsigned)__shfl_xor((int)m, s);
    m = o < m ? o : m;
  }
  return m;
}

#define FMA16(W)                                                      \
  a0 = fmaf(W[0][4*i+0], h4.x, a0); a0 = fmaf(W[0][4*i+1], h4.y, a0); \
  a0 = fmaf(W[0][4*i+2], h4.z, a0); a0 = fmaf(W[0][4*i+3], h4.w, a0); \
  a1 = fmaf(W[1][4*i+0], h4.x, a1); a1 = fmaf(W[1][4*i+1], h4.y, a1); \
  a1 = fmaf(W[1][4*i+2], h4.z, a1); a1 = fmaf(W[1][4*i+3], h4.w, a1); \
  a2 = fmaf(W[2][4*i+0], h4.x, a2); a2 = fmaf(W[2][4*i+1], h4.y, a2); \
  a2 = fmaf(W[2][4*i+2], h4.z, a2); a2 = fmaf(W[2][4*i+3], h4.w, a2); \
  a3 = fmaf(W[3][4*i+0], h4.x, a3); a3 = fmaf(W[3][4*i+1], h4.y, a3); \
  a3 = fmaf(W[3][4*i+2], h4.z, a3); a3 = fmaf(W[3][4*i+3], h4.w, a3);

__global__ void __launch_bounds__(512, 1) deepar_persistent(
    const float* __restrict__ obs,
    const float* __restrict__ Wih0, const float* __restrict__ Whh0, const float* __restrict__ b0,
    const float* __restrict__ Wih1, const float* __restrict__ Whh1, const float* __restrict__ b1,
    const float* __restrict__ Wdec, const float* __restrict__ bdec,
    float* __restrict__ out,
    unsigned* a_flag, unsigned* b_flag, unsigned* c_flag,
    float* h0_ring, float* h1_ring)
{
  const int wg  = blockIdx.x;
  const int tid = threadIdx.x;

  if (wg < NA) {
    //========== Group A: layer-0. 16 j's/WG; lane group = 32 lanes/j ==========
    const int rg = tid >> 5;          // 0..15  (j index within WG)
    const int q  = tid & 31;          // 0..31  (36-wide k-chunk of [h0;x])
    const int j  = wg * 16 + rg;
    const int k0 = q * 36;
    float w[4][36];                   // gate r of row j, k-chunk — ArchVGPR resident
    #pragma unroll
    for (int i = 0; i < 9; ++i) {
      const int kb = k0 + 4 * i;
      #pragma unroll
      for (int r = 0; r < 4; ++r) {
        const float* src = (kb < HH) ? (Whh0 + (size_t)(r * HH + j) * HH + kb)
                                     : (Wih0 + (size_t)(r * HH + j) * DD + (kb - HH));
        const float4 v = *(const float4*)src;
        w[r][4*i+0] = v.x; w[r][4*i+1] = v.y; w[r][4*i+2] = v.z; w[r][4*i+3] = v.w;
      }
    }
    float bs[4];
    #pragma unroll
    for (int r = 0; r < 4; ++r) bs[r] = b0[r * HH + j];
    float creg = 0.0f;
    unsigned bp = 0;   // cached min(b_flag) for ring backpressure (wave0 lanes)

    for (int t = 0; t < TT; ++t) {
      if (tid < 64) {
        const unsigned tg = (unsigned)t;                 // all A finished t-1
        while (!__all(ldrlx(&a_flag[tid]) >= tg)) {}
        if (t >= RINGN) {                                // B consumed h0(t-256)
          const unsigned need = (unsigned)(t - RINGN + 1);
          if (bp < need) {
            unsigned m;
            do {
              const unsigned u0 = ldrlx(&b_flag[tid]);
              const unsigned u1 = ldrlx(&b_flag[tid + 64]);
              m = wave_min(u0 < u1 ? u0 : u1);
            } while (m < need);
            bp = m;
          }
        }
      }
      __syncthreads();
      __builtin_amdgcn_fence(__ATOMIC_ACQUIRE, "agent");

      float a0 = 0.f, a1 = 0.f, a2 = 0.f, a3 = 0.f;
      if (t > 0) {
        const float* h0s = h0_ring + (size_t)((t - 1) & (RINGN - 1)) * HH;
        const float* obr = obs + (size_t)(t - 1) * DD;
        #pragma unroll
        for (int i = 0; i < 9; ++i) {
          const int kb = k0 + 4 * i;
          const float4 h4 = (kb < HH) ? *(const float4*)(h0s + kb)
                                      : *(const float4*)(obr + (kb - HH));
          FMA16(w)
        }
      }
      #pragma unroll
      for (int s = 1; s < 32; s <<= 1) {
        a0 += __shfl_xor(a0, s); a1 += __shfl_xor(a1, s);
        a2 += __shfl_xor(a2, s); a3 += __shfl_xor(a3, s);
      }
      if (q == 0) {
        const float ig = sigm(a0 + bs[0]);
        const float fg = sigm(a1 + bs[1]);
        const float gg = tanhf(a2 + bs[2]);
        const float og = sigm(a3 + bs[3]);
        creg = fg * creg + ig * gg;
        st_ring(&h0_ring[(size_t)(t & (RINGN - 1)) * HH + j], og * tanhf(creg));
      }
      __syncthreads();   // per-wave vmcnt(0) drain of ring stores before flag
      if (tid == 0) strel(&a_flag[wg], (unsigned)(t + 1));
    }

  } else if (wg < NA + NB) {
    //========== Group B: layer-1. 8 j's/WG; lane group = 64 lanes/j ==========
    const int rg = tid >> 6;          // 0..7
    const int q  = tid & 63;          // 0..63 (32-wide k-chunk of [h0(t); h1(t-1)])
    const int j  = (wg - NA) * 8 + rg;
    const int k0 = q * 32;
    float w[4][32];
    #pragma unroll
    for (int i = 0; i < 8; ++i) {
      const int kb = k0 + 4 * i;
      #pragma unroll
      for (int r = 0; r < 4; ++r) {
        const float* src = (kb < HH) ? (Wih1 + (size_t)(r * HH + j) * HH + kb)
                                     : (Whh1 + (size_t)(r * HH + j) * HH + (kb - HH));
        const float4 v = *(const float4*)src;
        w[r][4*i+0] = v.x; w[r][4*i+1] = v.y; w[r][4*i+2] = v.z; w[r][4*i+3] = v.w;
      }
    }
    float bs[4];
    #pragma unroll
    for (int r = 0; r < 4; ++r) bs[r] = b1[r * HH + j];
    float creg = 0.0f;
    unsigned bp = 0;

    for (int t = 0; t < TT; ++t) {
      if (tid < 64) {
        if (t > 0) {                                     // h1(t-1) ready
          const unsigned tg = (unsigned)t;
          while (!__all((ldrlx(&b_flag[tid]) >= tg) & (ldrlx(&b_flag[tid + 64]) >= tg))) {}
        }
        {                                                // h0(t) ready
          const unsigned tg = (unsigned)(t + 1);
          while (!__all(ldrlx(&a_flag[tid]) >= tg)) {}
        }
        if (t >= RINGN) {                                // C consumed h1(t-256)
          const unsigned need = (unsigned)(t - RINGN + 1);
          if (bp < need) {
            unsigned m;
            do {
              m = wave_min(tid < NC ? ldrlx(&c_flag[tid]) : 0xFFFFFFFFu);
            } while (m < need);
            bp = m;
          }
        }
      }
      __syncthreads();
      __builtin_amdgcn_fence(__ATOMIC_ACQUIRE, "agent");

      const float* h0s = h0_ring + (size_t)(t & (RINGN - 1)) * HH;
      const float* h1s = h1_ring + (size_t)((t - 1) & (RINGN - 1)) * HH;
      float a0 = 0.f, a1 = 0.f, a2 = 0.f, a3 = 0.f;
      #pragma unroll
      for (int i = 0; i < 8; ++i) {
        const int kb = k0 + 4 * i;
        float4 h4 = make_float4(0.f, 0.f, 0.f, 0.f);
        if (kb < HH)    h4 = *(const float4*)(h0s + kb);
        else if (t > 0) h4 = *(const float4*)(h1s + (kb - HH));
        FMA16(w)
      }
      #pragma unroll
      for (int s = 1; s < 64; s <<= 1) {
        a0 += __shfl_xor(a0, s); a1 += __shfl_xor(a1, s);
        a2 += __shfl_xor(a2, s); a3 += __shfl_xor(a3, s);
      }
      if (q == 0) {
        const float ig = sigm(a0 + bs[0]);
        const float fg = sigm(a1 + bs[1]);
        const float gg = tanhf(a2 + bs[2]);
        const float og = sigm(a3 + bs[3]);
        creg = fg * creg + ig * gg;
        st_ring(&h1_ring[(size_t)(t & (RINGN - 1)) * HH + j], og * tanhf(creg));
      }
      __syncthreads();
      if (tid == 0) strel(&b_flag[wg - NA], (unsigned)(t + 1));
    }

  } else {
    //========== Group C: decoder. 16 rows/WG; 2 rows per 64-lane group ==========
    const int rg = tid >> 6;          // 0..7
    const int q  = tid & 63;          // 16-wide k-chunk of h1
    const int rowbase = (wg - NA - NB) * 16;
    const int row0 = rowbase + 2 * rg;
    const int k0 = q * 16;
    float w[2][16];
    #pragma unroll
    for (int i = 0; i < 4; ++i) {
      const int kb = k0 + 4 * i;
      #pragma unroll
      for (int r = 0; r < 2; ++r) {
        const float4 v = *(const float4*)(Wdec + (size_t)(row0 + r) * HH + kb);
        w[r][4*i+0] = v.x; w[r][4*i+1] = v.y; w[r][4*i+2] = v.z; w[r][4*i+3] = v.w;
      }
    }
    const float bs0 = bdec[row0], bs1 = bdec[row0 + 1];

    for (int t = 0; t < TT; ++t) {
      if (tid < 64) {
        const unsigned tg = (unsigned)(t + 1);           // h1(t) ready
        while (!__all((ldrlx(&b_flag[tid]) >= tg) & (ldrlx(&b_flag[tid + 64]) >= tg))) {}
      }
      __syncthreads();
      __builtin_amdgcn_fence(__ATOMIC_ACQUIRE, "agent");

      const float* h1s = h1_ring + (size_t)(t & (RINGN - 1)) * HH;
      float a0 = 0.f, a1 = 0.f;
      #pragma unroll
      for (int i = 0; i < 4; ++i) {
        const int kb = k0 + 4 * i;
        const float4 h4 = *(const float4*)(h1s + kb);
        a0 = fmaf(w[0][4*i+0], h4.x, a0); a0 = fmaf(w[0][4*i+1], h4.y, a0);
        a0 = fmaf(w[0][4*i+2], h4.z, a0); a0 = fmaf(w[0][4*i+3], h4.w, a0);
        a1 = fmaf(w[1][4*i+0], h4.x, a1); a1 = fmaf(w[1][4*i+1], h4.y, a1);
        a1 = fmaf(w[1][4*i+2], h4.z, a1); a1 = fmaf(w[1][4*i+3], h4.w, a1);
      }
      #pragma unroll
      for (int s = 1; s < 64; s <<= 1) { a0 += __shfl_xor(a0, s); a1 += __shfl_xor(a1, s); }
      if (q == 0) {
        const float z0 = a0 + bs0;
        const float z1 = a1 + bs1;
        if (row0 < DD) {
          out[(size_t)t * DD + row0]     = z0;
          out[(size_t)t * DD + row0 + 1] = z1;
        } else {
          out[(size_t)TT * DD + (size_t)t * DD + (row0 - DD)]     = softplusf(z0) + 1e-4f;
          out[(size_t)TT * DD + (size_t)t * DD + (row0 - DD) + 1] = softplusf(z1) + 1e-4f;
        }
      }
      __syncthreads();   // all waves' h1 reads retired before releasing the slot
      if (tid == 0) strel(&c_flag[wg - NA - NB], (unsigned)(t + 1));
    }
  }
}

extern "C" void kernel_launch(void* const* d_in, const int* in_sizes, int n_in,
                              void* d_out, int out_size, void* d_ws, size_t ws_size,
                              hipStream_t stream) {
  const float* obs  = (const float*)d_in[0];
  const float* Wih0 = (const float*)d_in[1];
  const float* Whh0 = (const float*)d_in[2];
  const float* b0   = (const float*)d_in[3];
  const float* Wih1 = (const float*)d_in[4];
  const float* Whh1 = (const float*)d_in[5];
  const float* b1   = (const float*)d_in[6];
  const float* Wdec = (const float*)d_in[7];
  const float* bdec = (const float*)d_in[8];
  float* out = (float*)d_out;

  unsigned char* ws = (unsigned char*)d_ws;
  unsigned* a_flag = (unsigned*)(ws);
  unsigned* b_flag = (unsigned*)(ws + 512);
  unsigned* c_flag = (unsigned*)(ws + 1536);
  float* h0_ring = (float*)(ws + 131072);
  float* h1_ring = (float*)(ws + 131072 + (size_t)RINGN * HH * 4);

  // epoch flags must start at 0 every call (graph replays; no harness re-poison)
  hipMemsetAsync(ws, 0, 4096, stream);

  hipLaunchKernelGGL(deepar_persistent, dim3(NWG), dim3(512), 0, stream,
                     obs, Wih0, Whh0, b0, Wih1, Whh1, b1, Wdec, bdec, out,
                     a_flag, b_flag, c_flag, h0_ring, h1_ring);
}

// Round 3
// 35999.799 us; speedup vs baseline: 4.3412x; 4.3412x over previous
//
#include <hip/hip_runtime.h>
#include <math.h>

#define TT 8192
#define DD 128
#define HH 1024
#define RINGN 256          // ring slots (power of 2)
#define NA 64              // layer-0 workgroups
#define NB 128             // layer-1 workgroups
#define NC 16              // decoder workgroups
#define NWG (NA + NB + NC)

// d_ws layout (bytes):
//   [0)      a_flag u32[64]    per-WG epoch (steps completed)
//   [512)    b_flag u32[128]
//   [1536)   c_flag u32[16]
//   [131072) h0_ring f32[RINGN][HH]
//   [131072 + RINGN*HH*4) h1_ring f32[RINGN][HH]
// NO fences anywhere: rings+flags are relaxed agent-scope atomics (bypass
// non-coherent L1/L2, served at the coherence point). Ordering ring-stores
// -> flag-store comes from the vmcnt(0) drain __syncthreads performs.

__device__ __forceinline__ unsigned ldflag(const unsigned* p) {
  return __hip_atomic_load(p, __ATOMIC_RELAXED, __HIP_MEMORY_SCOPE_AGENT);
}
__device__ __forceinline__ void stflag(unsigned* p, unsigned v) {
  __hip_atomic_store(p, v, __ATOMIC_RELAXED, __HIP_MEMORY_SCOPE_AGENT);
}
__device__ __forceinline__ float ldring(const float* p) {
  return __hip_atomic_load(p, __ATOMIC_RELAXED, __HIP_MEMORY_SCOPE_AGENT);
}
__device__ __forceinline__ void st_ring(float* p, float v) {
  __hip_atomic_store(p, v, __ATOMIC_RELAXED, __HIP_MEMORY_SCOPE_AGENT);
}
__device__ __forceinline__ float sigm(float x) { return 1.0f / (1.0f + expf(-x)); }
__device__ __forceinline__ float softplusf(float x) {
  return x > 0.0f ? x + log1pf(expf(-x)) : log1pf(expf(x));
}

#define FMA16(W)                                                      \
  a0 = fmaf(W[0][4*i+0], h4.x, a0); a0 = fmaf(W[0][4*i+1], h4.y, a0); \
  a0 = fmaf(W[0][4*i+2], h4.z, a0); a0 = fmaf(W[0][4*i+3], h4.w, a0); \
  a1 = fmaf(W[1][4*i+0], h4.x, a1); a1 = fmaf(W[1][4*i+1], h4.y, a1); \
  a1 = fmaf(W[1][4*i+2], h4.z, a1); a1 = fmaf(W[1][4*i+3], h4.w, a1); \
  a2 = fmaf(W[2][4*i+0], h4.x, a2); a2 = fmaf(W[2][4*i+1], h4.y, a2); \
  a2 = fmaf(W[2][4*i+2], h4.z, a2); a2 = fmaf(W[2][4*i+3], h4.w, a2); \
  a3 = fmaf(W[3][4*i+0], h4.x, a3); a3 = fmaf(W[3][4*i+1], h4.y, a3); \
  a3 = fmaf(W[3][4*i+2], h4.z, a3); a3 = fmaf(W[3][4*i+3], h4.w, a3);

__global__ void __launch_bounds__(512, 1) deepar_persistent(
    const float* __restrict__ obs,
    const float* __restrict__ Wih0, const float* __restrict__ Whh0, const float* __restrict__ b0,
    const float* __restrict__ Wih1, const float* __restrict__ Whh1, const float* __restrict__ b1,
    const float* __restrict__ Wdec, const float* __restrict__ bdec,
    float* __restrict__ out,
    unsigned* a_flag, unsigned* b_flag, unsigned* c_flag,
    float* h0_ring, float* h1_ring)
{
  __shared__ __align__(16) float hx[2304];   // A: [0,1024) unpadded; B/C: padded layouts

  const int wg  = blockIdx.x;
  const int tid = threadIdx.x;

  if (wg < NA) {
    //========== Group A: layer-0. 16 j's/WG; 32 lanes per j ==========
    const int rg = tid >> 5;          // 0..15  (j within WG)
    const int q  = tid & 31;          // 36-wide k-slice of [h0(1024); x(128)]
    const int j  = wg * 16 + rg;
    const int k0 = q * 36;
    float w[4][36];                   // on-chip (VGPR+AGPR unified file)
    #pragma unroll
    for (int i = 0; i < 9; ++i) {
      const int kb = k0 + 4 * i;
      #pragma unroll
      for (int r = 0; r < 4; ++r) {
        const float* src = (kb < HH) ? (Whh0 + (size_t)(r * HH + j) * HH + kb)
                                     : (Wih0 + (size_t)(r * HH + j) * DD + (kb - HH));
        const float4 v = *(const float4*)src;
        w[r][4*i+0] = v.x; w[r][4*i+1] = v.y; w[r][4*i+2] = v.z; w[r][4*i+3] = v.w;
      }
    }
    float bs[4];
    #pragma unroll
    for (int r = 0; r < 4; ++r) bs[r] = b0[r * HH + j];
    float creg = 0.0f;

    for (int t = 0; t < TT; ++t) {
      float a0 = 0.f, a1 = 0.f, a2 = 0.f, a3 = 0.f;
      if (t > 0) {
        // x-part first (obs is read-only + cached; overlaps the sibling wait)
        const float* obr = obs + (size_t)(t - 1) * DD;
        #pragma unroll
        for (int i = 0; i < 9; ++i) {
          const int kb = k0 + 4 * i;
          if (kb >= HH) { const float4 h4 = *(const float4*)(obr + (kb - HH)); FMA16(w) }
        }
        if (tid < 64) {                                   // wave0 polls
          const unsigned tg = (unsigned)t;                // siblings done t-1
          while (!__all((tid == wg) | (ldflag(&a_flag[tid]) >= tg))) {}
          if (t >= RINGN) {                               // B consumed h0(t-256)
            const unsigned need = (unsigned)(t - RINGN + 1);
            while (!__all((ldflag(&b_flag[tid]) >= need) &
                          (ldflag(&b_flag[tid + 64]) >= need))) {}
          }
        }
        __syncthreads();
        {                                                 // stage h0(t-1) -> LDS once
          const float* h0s = h0_ring + (size_t)((t - 1) & (RINGN - 1)) * HH;
          hx[tid]       = ldring(h0s + tid);
          hx[tid + 512] = ldring(h0s + tid + 512);
        }
        __syncthreads();
        #pragma unroll
        for (int i = 0; i < 9; ++i) {
          const int kb = k0 + 4 * i;
          if (kb < HH) { const float4 h4 = *(const float4*)&hx[kb]; FMA16(w) }
        }
      }
      #pragma unroll
      for (int s = 1; s < 32; s <<= 1) {
        a0 += __shfl_xor(a0, s); a1 += __shfl_xor(a1, s);
        a2 += __shfl_xor(a2, s); a3 += __shfl_xor(a3, s);
      }
      if (q == 0) {
        const float ig = sigm(a0 + bs[0]);
        const float fg = sigm(a1 + bs[1]);
        const float gg = tanhf(a2 + bs[2]);
        const float og = sigm(a3 + bs[3]);
        creg = fg * creg + ig * gg;
        st_ring(&h0_ring[(size_t)(t & (RINGN - 1)) * HH + j], og * tanhf(creg));
      }
      __syncthreads();                                    // vmcnt(0) drain of ring stores
      if (tid == 0) stflag(&a_flag[wg], (unsigned)(t + 1));
    }

  } else if (wg < NA + NB) {
    //========== Group B: layer-1. 8 j's/WG; 64 lanes per j ==========
    const int rg = tid >> 6;          // 0..7
    const int q  = tid & 63;          // 32-wide k-slice of [h0(t); h1(t-1)]
    const int s_ = wg - NA;           // own flag index
    const int j  = s_ * 8 + rg;
    const int k0 = q * 32;
    float w[4][32];
    #pragma unroll
    for (int i = 0; i < 8; ++i) {
      const int kb = k0 + 4 * i;
      #pragma unroll
      for (int r = 0; r < 4; ++r) {
        const float* src = (kb < HH) ? (Wih1 + (size_t)(r * HH + j) * HH + kb)
                                     : (Whh1 + (size_t)(r * HH + j) * HH + (kb - HH));
        const float4 v = *(const float4*)src;
        w[r][4*i+0] = v.x; w[r][4*i+1] = v.y; w[r][4*i+2] = v.z; w[r][4*i+3] = v.w;
      }
    }
    float bs[4];
    #pragma unroll
    for (int r = 0; r < 4; ++r) bs[r] = b1[r * HH + j];
    float creg = 0.0f;

    for (int t = 0; t < TT; ++t) {
      if (tid < 64) {                                     // one combined poll phase
        const unsigned needA = (unsigned)(t + 1);         // h0(t) ready
        const unsigned needB = (unsigned)t;               // h1(t-1) ready
        const unsigned needC = (t >= RINGN) ? (unsigned)(t - RINGN + 1) : 0u;
        for (;;) {
          int ok = (ldflag(&a_flag[tid]) >= needA);
          if (t > 0) {
            ok &= (tid == s_)      | (ldflag(&b_flag[tid])      >= needB);
            ok &= ((tid + 64) == s_) | (ldflag(&b_flag[tid + 64]) >= needB);
          }
          if (needC) ok &= (tid >= NC) | (ldflag(&c_flag[tid]) >= needC);
          if (__all(ok)) break;
        }
      }
      __syncthreads();
      {                                                   // stage [h0(t); h1(t-1)] -> LDS
        const float* h0s = h0_ring + (size_t)(t & (RINGN - 1)) * HH;
        const float* h1s = h1_ring + (size_t)((t - 1) & (RINGN - 1)) * HH;
        int idx = tid;                                    // reps 0,1: h0
        hx[idx + ((idx >> 5) << 2)] = ldring(h0s + idx);
        idx = tid + 512;
        hx[idx + ((idx >> 5) << 2)] = ldring(h0s + idx);
        idx = tid + 1024;                                 // reps 2,3: h1(t-1)
        hx[idx + ((idx >> 5) << 2)] = (t > 0) ? ldring(h1s + (idx - HH)) : 0.0f;
        idx = tid + 1536;
        hx[idx + ((idx >> 5) << 2)] = (t > 0) ? ldring(h1s + (idx - HH)) : 0.0f;
      }
      __syncthreads();
      float a0 = 0.f, a1 = 0.f, a2 = 0.f, a3 = 0.f;
      {
        const int base = q * 36;                          // padded: k + 4*(k>>5)
        #pragma unroll
        for (int i = 0; i < 8; ++i) {
          const float4 h4 = *(const float4*)&hx[base + 4 * i];
          FMA16(w)
        }
      }
      #pragma unroll
      for (int s = 1; s < 64; s <<= 1) {
        a0 += __shfl_xor(a0, s); a1 += __shfl_xor(a1, s);
        a2 += __shfl_xor(a2, s); a3 += __shfl_xor(a3, s);
      }
      if (q == 0) {
        const float ig = sigm(a0 + bs[0]);
        const float fg = sigm(a1 + bs[1]);
        const float gg = tanhf(a2 + bs[2]);
        const float og = sigm(a3 + bs[3]);
        creg = fg * creg + ig * gg;
        st_ring(&h1_ring[(size_t)(t & (RINGN - 1)) * HH + j], og * tanhf(creg));
      }
      __syncthreads();
      if (tid == 0) stflag(&b_flag[s_], (unsigned)(t + 1));
    }

  } else {
    //========== Group C: decoder. 16 rows/WG; 2 rows per 64-lane group ==========
    const int rg = tid >> 6;          // 0..7
    const int q  = tid & 63;          // 16-wide k-slice of h1
    const int rowbase = (wg - NA - NB) * 16;
    const int row0 = rowbase + 2 * rg;
    const int k0 = q * 16;
    float w[2][16];
    #pragma unroll
    for (int i = 0; i < 4; ++i) {
      const int kb = k0 + 4 * i;
      #pragma unroll
      for (int r = 0; r < 2; ++r) {
        const float4 v = *(const float4*)(Wdec + (size_t)(row0 + r) * HH + kb);
        w[r][4*i+0] = v.x; w[r][4*i+1] = v.y; w[r][4*i+2] = v.z; w[r][4*i+3] = v.w;
      }
    }
    const float bs0 = bdec[row0], bs1 = bdec[row0 + 1];

    for (int t = 0; t < TT; ++t) {
      if (tid < 64) {
        const unsigned tg = (unsigned)(t + 1);            // h1(t) ready
        while (!__all((ldflag(&b_flag[tid]) >= tg) &
                      (ldflag(&b_flag[tid + 64]) >= tg))) {}
      }
      __syncthreads();
      {                                                   // stage h1(t) -> LDS
        const float* h1s = h1_ring + (size_t)(t & (RINGN - 1)) * HH;
        hx[tid + ((tid >> 4) << 2)] = ldring(h1s + tid);
        const int i2 = tid + 512;
        hx[i2 + ((i2 >> 4) << 2)] = ldring(h1s + i2);
      }
      __syncthreads();
      float a0 = 0.f, a1 = 0.f;
      {
        const int base = q * 20;                          // padded: k + 4*(k>>4)
        #pragma unroll
        for (int i = 0; i < 4; ++i) {
          const float4 h4 = *(const float4*)&hx[base + 4 * i];
          a0 = fmaf(w[0][4*i+0], h4.x, a0); a0 = fmaf(w[0][4*i+1], h4.y, a0);
          a0 = fmaf(w[0][4*i+2], h4.z, a0); a0 = fmaf(w[0][4*i+3], h4.w, a0);
          a1 = fmaf(w[1][4*i+0], h4.x, a1); a1 = fmaf(w[1][4*i+1], h4.y, a1);
          a1 = fmaf(w[1][4*i+2], h4.z, a1); a1 = fmaf(w[1][4*i+3], h4.w, a1);
        }
      }
      #pragma unroll
      for (int s = 1; s < 64; s <<= 1) { a0 += __shfl_xor(a0, s); a1 += __shfl_xor(a1, s); }
      if (q == 0) {
        const float z0 = a0 + bs0;
        const float z1 = a1 + bs1;
        if (row0 < DD) {
          out[(size_t)t * DD + row0]     = z0;            // loc (plain cached stores)
          out[(size_t)t * DD + row0 + 1] = z1;
        } else {
          out[(size_t)TT * DD + (size_t)t * DD + (row0 - DD)]     = softplusf(z0) + 1e-4f;
          out[(size_t)TT * DD + (size_t)t * DD + (row0 - DD) + 1] = softplusf(z1) + 1e-4f;
        }
      }
      __syncthreads();                                    // h1 slot fully consumed
      if (tid == 0) stflag(&c_flag[wg - NA - NB], (unsigned)(t + 1));
    }
  }
}

extern "C" void kernel_launch(void* const* d_in, const int* in_sizes, int n_in,
                              void* d_out, int out_size, void* d_ws, size_t ws_size,
                              hipStream_t stream) {
  const float* obs  = (const float*)d_in[0];
  const float* Wih0 = (const float*)d_in[1];
  const float* Whh0 = (const float*)d_in[2];
  const float* b0   = (const float*)d_in[3];
  const float* Wih1 = (const float*)d_in[4];
  const float* Whh1 = (const float*)d_in[5];
  const float* b1   = (const float*)d_in[6];
  const float* Wdec = (const float*)d_in[7];
  const float* bdec = (const float*)d_in[8];
  float* out = (float*)d_out;

  unsigned char* ws = (unsigned char*)d_ws;
  unsigned* a_flag = (unsigned*)(ws);
  unsigned* b_flag = (unsigned*)(ws + 512);
  unsigned* c_flag = (unsigned*)(ws + 1536);
  float* h0_ring = (float*)(ws + 131072);
  float* h1_ring = (float*)(ws + 131072 + (size_t)RINGN * HH * 4);

  // epoch flags must start at 0 every call (graph replay; no harness re-poison)
  hipMemsetAsync(ws, 0, 4096, stream);

  hipLaunchKernelGGL(deepar_persistent, dim3(NWG), dim3(512), 0, stream,
                     obs, Wih0, Whh0, b0, Wih1, Whh1, b1, Wdec, bdec, out,
                     a_flag, b_flag, c_flag, h0_ring, h1_ring);
}

// Round 4
// 32205.954 us; speedup vs baseline: 4.8525x; 1.1178x over previous
//
#include <hip/hip_runtime.h>
#include <math.h>

#define TT 8192
#define DD 128
#define HH 1024
#define RINGN 64           // ring slots (power of 2); actual lag ~1-2 steps
#define NA 64              // layer-0 workgroups
#define NB 128             // layer-1 workgroups
#define NC 16              // decoder workgroups
#define NWG (NA + NB + NC)

// d_ws layout (bytes):
//   [0)     b_cons u32[128]  B's consumption epoch of h0 (for A's ring reuse)
//   [512)   c_cons u32[16]   C's consumption epoch of h1 (for B's ring reuse)
//   [4096)  h0_ring ull[RINGN][HH]   (value f32 | epoch u32) packed pairs
//   [4096 + RINGN*HH*8) h1_ring ull[RINGN][HH]
// Sync protocol: producers store (value, step+1) as ONE relaxed 8B agent
// atomic. Consumers poll pairs directly until epoch matches. No flags on the
// critical path, no fences, no release semantics (avoids L2 writeback storms).
// Rings are memset to 0 each call: epoch 0 == "initial zero state".

typedef unsigned long long ull;

__device__ __forceinline__ ull ldpair(const ull* p) {
  return __hip_atomic_load(p, __ATOMIC_RELAXED, __HIP_MEMORY_SCOPE_AGENT);
}
__device__ __forceinline__ void stpair(ull* p, float v, unsigned e) {
  ull u = ((ull)e << 32) | (ull)__float_as_uint(v);
  __hip_atomic_store(p, u, __ATOMIC_RELAXED, __HIP_MEMORY_SCOPE_AGENT);
}
__device__ __forceinline__ unsigned ldflag(const unsigned* p) {
  return __hip_atomic_load(p, __ATOMIC_RELAXED, __HIP_MEMORY_SCOPE_AGENT);
}
__device__ __forceinline__ void stflag(unsigned* p, unsigned v) {
  __hip_atomic_store(p, v, __ATOMIC_RELAXED, __HIP_MEMORY_SCOPE_AGENT);
}
__device__ __forceinline__ float sigm(float x) { return 1.0f / (1.0f + expf(-x)); }
__device__ __forceinline__ float softplusf(float x) {
  return x > 0.0f ? x + log1pf(expf(-x)) : log1pf(expf(x));
}

#define FMA16(W)                                                      \
  a0 = fmaf(W[0][4*i+0], h4.x, a0); a0 = fmaf(W[0][4*i+1], h4.y, a0); \
  a0 = fmaf(W[0][4*i+2], h4.z, a0); a0 = fmaf(W[0][4*i+3], h4.w, a0); \
  a1 = fmaf(W[1][4*i+0], h4.x, a1); a1 = fmaf(W[1][4*i+1], h4.y, a1); \
  a1 = fmaf(W[1][4*i+2], h4.z, a1); a1 = fmaf(W[1][4*i+3], h4.w, a1); \
  a2 = fmaf(W[2][4*i+0], h4.x, a2); a2 = fmaf(W[2][4*i+1], h4.y, a2); \
  a2 = fmaf(W[2][4*i+2], h4.z, a2); a2 = fmaf(W[2][4*i+3], h4.w, a2); \
  a3 = fmaf(W[3][4*i+0], h4.x, a3); a3 = fmaf(W[3][4*i+1], h4.y, a3); \
  a3 = fmaf(W[3][4*i+2], h4.z, a3); a3 = fmaf(W[3][4*i+3], h4.w, a3);

__global__ void __launch_bounds__(512, 1) deepar_persistent(
    const float* __restrict__ obs,
    const float* __restrict__ Wih0, const float* __restrict__ Whh0, const float* __restrict__ b0,
    const float* __restrict__ Wih1, const float* __restrict__ Whh1, const float* __restrict__ b1,
    const float* __restrict__ Wdec, const float* __restrict__ bdec,
    float* __restrict__ out,
    unsigned* b_cons, unsigned* c_cons,
    ull* h0_ring, ull* h1_ring)
{
  __shared__ __align__(16) float hx[2][2304];   // double-buffered staged h

  const int wg  = blockIdx.x;
  const int tid = threadIdx.x;

  if (wg < NA) {
    //========== Group A: layer-0. 16 j's/WG; 32 lanes per j ==========
    const int rg = tid >> 5;          // 0..15 (j within WG)
    const int q  = tid & 31;          // 36-wide k-slice of [h0(1024); x(128)]
    const int j  = wg * 16 + rg;
    const int k0 = q * 36;
    float w[4][36];                   // on-chip weights (unified VGPR/AGPR file)
    #pragma unroll
    for (int i = 0; i < 9; ++i) {
      const int kb = k0 + 4 * i;
      #pragma unroll
      for (int r = 0; r < 4; ++r) {
        const float* src = (kb < HH) ? (Whh0 + (size_t)(r * HH + j) * HH + kb)
                                     : (Wih0 + (size_t)(r * HH + j) * DD + (kb - HH));
        const float4 v = *(const float4*)src;
        w[r][4*i+0] = v.x; w[r][4*i+1] = v.y; w[r][4*i+2] = v.z; w[r][4*i+3] = v.w;
      }
    }
    float bs[4];
    #pragma unroll
    for (int r = 0; r < 4; ++r) bs[r] = b0[r * HH + j];
    float creg = 0.0f;

    for (int t = 0; t < TT; ++t) {
      float a0 = 0.f, a1 = 0.f, a2 = 0.f, a3 = 0.f;
      // x-part first (read-only cached loads; overlaps producer-store latency)
      if (t > 0) {
        const float* obr = obs + (size_t)(t - 1) * DD;
        #pragma unroll
        for (int i = 0; i < 9; ++i) {
          const int kb = k0 + 4 * i;
          if (kb >= HH) { const float4 h4 = *(const float4*)(obr + (kb - HH)); FMA16(w) }
        }
      }
      // amortized ring-reuse backpressure (off critical path, every 16 steps)
      if (((t & 15) == 0) && t >= 48 && tid < 64) {
        const unsigned need = (unsigned)(t - 32);
        while (!__all((ldflag(&b_cons[tid]) >= need) &
                      (ldflag(&b_cons[tid + 64]) >= need))) {}
      }
      // stage h0(t-1): poll (value,epoch) pairs directly, deposit into LDS
      float* Lb = hx[t & 1];
      {
        const ull* sl = h0_ring + (size_t)((t - 1) & (RINGN - 1)) * HH;
        const unsigned ee = (unsigned)t;
        bool d0 = false, d1 = false;
        do {
          ull u0 = 0, u1 = 0;
          if (!d0) u0 = ldpair(sl + tid);
          if (!d1) u1 = ldpair(sl + tid + 512);
          if (!d0 && (unsigned)(u0 >> 32) == ee) { Lb[tid]       = __uint_as_float((unsigned)u0); d0 = true; }
          if (!d1 && (unsigned)(u1 >> 32) == ee) { Lb[tid + 512] = __uint_as_float((unsigned)u1); d1 = true; }
        } while (!(d0 & d1));
      }
      __syncthreads();                 // the ONLY barrier per step
      #pragma unroll
      for (int i = 0; i < 9; ++i) {
        const int kb = k0 + 4 * i;
        if (kb < HH) { const float4 h4 = *(const float4*)&Lb[kb]; FMA16(w) }
      }
      #pragma unroll
      for (int s = 1; s < 32; s <<= 1) {
        a0 += __shfl_xor(a0, s); a1 += __shfl_xor(a1, s);
        a2 += __shfl_xor(a2, s); a3 += __shfl_xor(a3, s);
      }
      if (q == 0) {
        const float ig = sigm(a0 + bs[0]);
        const float fg = sigm(a1 + bs[1]);
        const float gg = tanhf(a2 + bs[2]);
        const float og = sigm(a3 + bs[3]);
        creg = fg * creg + ig * gg;
        stpair(&h0_ring[(size_t)(t & (RINGN - 1)) * HH + j], og * tanhf(creg),
               (unsigned)(t + 1));
      }
    }

  } else if (wg < NA + NB) {
    //========== Group B: layer-1. 8 j's/WG; 64 lanes per j ==========
    const int rg = tid >> 6;          // 0..7
    const int q  = tid & 63;          // 32-wide k-slice of [h0(t); h1(t-1)]
    const int s_ = wg - NA;
    const int j  = s_ * 8 + rg;
    const int k0 = q * 32;
    float w[4][32];
    #pragma unroll
    for (int i = 0; i < 8; ++i) {
      const int kb = k0 + 4 * i;
      #pragma unroll
      for (int r = 0; r < 4; ++r) {
        const float* src = (kb < HH) ? (Wih1 + (size_t)(r * HH + j) * HH + kb)
                                     : (Whh1 + (size_t)(r * HH + j) * HH + (kb - HH));
        const float4 v = *(const float4*)src;
        w[r][4*i+0] = v.x; w[r][4*i+1] = v.y; w[r][4*i+2] = v.z; w[r][4*i+3] = v.w;
      }
    }
    float bs[4];
    #pragma unroll
    for (int r = 0; r < 4; ++r) bs[r] = b1[r * HH + j];
    float creg = 0.0f;
    // padded LDS positions: element e -> e + 4*(e>>5)
    const int p0 = tid + 4 * (tid >> 5);      // h0 elem tid
    const int p1 = p0 + 576;                  // h0 elem tid+512
    const int p2 = p0 + 1152;                 // h1 elem tid
    const int p3 = p2 + 576;                  // h1 elem tid+512

    for (int t = 0; t < TT; ++t) {
      if (((t & 15) == 0) && t >= 48 && tid < 64) {   // C's h1 consumption
        const unsigned need = (unsigned)(t - 32);
        while (!__all((tid >= NC) | (ldflag(&c_cons[tid]) >= need))) {}
      }
      float* Lb = hx[t & 1];
      {
        const ull* s0 = h0_ring + (size_t)(t & (RINGN - 1)) * HH;
        const ull* s1 = h1_ring + (size_t)((t - 1) & (RINGN - 1)) * HH;
        const unsigned e0 = (unsigned)(t + 1);        // h0(t)
        const unsigned e1 = (unsigned)t;              // h1(t-1)
        bool d0 = false, d1 = false, d2 = false, d3 = false;
        do {
          ull u0 = 0, u1 = 0, u2 = 0, u3 = 0;
          if (!d0) u0 = ldpair(s0 + tid);
          if (!d1) u1 = ldpair(s0 + tid + 512);
          if (!d2) u2 = ldpair(s1 + tid);
          if (!d3) u3 = ldpair(s1 + tid + 512);
          if (!d0 && (unsigned)(u0 >> 32) == e0) { Lb[p0] = __uint_as_float((unsigned)u0); d0 = true; }
          if (!d1 && (unsigned)(u1 >> 32) == e0) { Lb[p1] = __uint_as_float((unsigned)u1); d1 = true; }
          if (!d2 && (unsigned)(u2 >> 32) == e1) { Lb[p2] = __uint_as_float((unsigned)u2); d2 = true; }
          if (!d3 && (unsigned)(u3 >> 32) == e1) { Lb[p3] = __uint_as_float((unsigned)u3); d3 = true; }
        } while (!(d0 & d1 & d2 & d3));
      }
      __syncthreads();
      if (tid == 0) stflag(&b_cons[s_], (unsigned)(t + 1));  // h0(t) consumed
      float a0 = 0.f, a1 = 0.f, a2 = 0.f, a3 = 0.f;
      {
        const int base = q * 36;       // padded k-slice base
        #pragma unroll
        for (int i = 0; i < 8; ++i) {
          const float4 h4 = *(const float4*)&Lb[base + 4 * i];
          FMA16(w)
        }
      }
      #pragma unroll
      for (int s = 1; s < 64; s <<= 1) {
        a0 += __shfl_xor(a0, s); a1 += __shfl_xor(a1, s);
        a2 += __shfl_xor(a2, s); a3 += __shfl_xor(a3, s);
      }
      if (q == 0) {
        const float ig = sigm(a0 + bs[0]);
        const float fg = sigm(a1 + bs[1]);
        const float gg = tanhf(a2 + bs[2]);
        const float og = sigm(a3 + bs[3]);
        creg = fg * creg + ig * gg;
        stpair(&h1_ring[(size_t)(t & (RINGN - 1)) * HH + j], og * tanhf(creg),
               (unsigned)(t + 1));
      }
    }

  } else {
    //========== Group C: decoder. 16 rows/WG; 2 rows per 64-lane group ==========
    const int rg = tid >> 6;          // 0..7
    const int q  = tid & 63;          // 16-wide k-slice of h1
    const int cg = wg - NA - NB;
    const int rowbase = cg * 16;
    const int row0 = rowbase + 2 * rg;
    const int k0 = q * 16;
    float w[2][16];
    #pragma unroll
    for (int i = 0; i < 4; ++i) {
      const int kb = k0 + 4 * i;
      #pragma unroll
      for (int r = 0; r < 2; ++r) {
        const float4 v = *(const float4*)(Wdec + (size_t)(row0 + r) * HH + kb);
        w[r][4*i+0] = v.x; w[r][4*i+1] = v.y; w[r][4*i+2] = v.z; w[r][4*i+3] = v.w;
      }
    }
    const float bs0 = bdec[row0], bs1 = bdec[row0 + 1];
    const int pc0 = tid + 4 * (tid >> 4);     // padded: e + 4*(e>>4)
    const int pc1 = pc0 + 640;                // elem tid+512

    for (int t = 0; t < TT; ++t) {
      float* Lb = hx[t & 1];
      {
        const ull* sl = h1_ring + (size_t)(t & (RINGN - 1)) * HH;
        const unsigned ee = (unsigned)(t + 1);
        bool d0 = false, d1 = false;
        do {
          ull u0 = 0, u1 = 0;
          if (!d0) u0 = ldpair(sl + tid);
          if (!d1) u1 = ldpair(sl + tid + 512);
          if (!d0 && (unsigned)(u0 >> 32) == ee) { Lb[pc0] = __uint_as_float((unsigned)u0); d0 = true; }
          if (!d1 && (unsigned)(u1 >> 32) == ee) { Lb[pc1] = __uint_as_float((unsigned)u1); d1 = true; }
        } while (!(d0 & d1));
      }
      __syncthreads();
      if (tid == 0) stflag(&c_cons[cg], (unsigned)(t + 1));  // h1(t) consumed
      float a0 = 0.f, a1 = 0.f;
      {
        const int base = q * 20;
        #pragma unroll
        for (int i = 0; i < 4; ++i) {
          const float4 h4 = *(const float4*)&Lb[base + 4 * i];
          a0 = fmaf(w[0][4*i+0], h4.x, a0); a0 = fmaf(w[0][4*i+1], h4.y, a0);
          a0 = fmaf(w[0][4*i+2], h4.z, a0); a0 = fmaf(w[0][4*i+3], h4.w, a0);
          a1 = fmaf(w[1][4*i+0], h4.x, a1); a1 = fmaf(w[1][4*i+1], h4.y, a1);
          a1 = fmaf(w[1][4*i+2], h4.z, a1); a1 = fmaf(w[1][4*i+3], h4.w, a1);
        }
      }
      #pragma unroll
      for (int s = 1; s < 64; s <<= 1) { a0 += __shfl_xor(a0, s); a1 += __shfl_xor(a1, s); }
      if (q == 0) {
        const float z0 = a0 + bs0;
        const float z1 = a1 + bs1;
        if (row0 < DD) {
          out[(size_t)t * DD + row0]     = z0;
          out[(size_t)t * DD + row0 + 1] = z1;
        } else {
          out[(size_t)TT * DD + (size_t)t * DD + (row0 - DD)]     = softplusf(z0) + 1e-4f;
          out[(size_t)TT * DD + (size_t)t * DD + (row0 - DD) + 1] = softplusf(z1) + 1e-4f;
        }
      }
    }
  }
}

extern "C" void kernel_launch(void* const* d_in, const int* in_sizes, int n_in,
                              void* d_out, int out_size, void* d_ws, size_t ws_size,
                              hipStream_t stream) {
  const float* obs  = (const float*)d_in[0];
  const float* Wih0 = (const float*)d_in[1];
  const float* Whh0 = (const float*)d_in[2];
  const float* b0   = (const float*)d_in[3];
  const float* Wih1 = (const float*)d_in[4];
  const float* Whh1 = (const float*)d_in[5];
  const float* b1   = (const float*)d_in[6];
  const float* Wdec = (const float*)d_in[7];
  const float* bdec = (const float*)d_in[8];
  float* out = (float*)d_out;

  unsigned char* ws = (unsigned char*)d_ws;
  unsigned* b_cons = (unsigned*)(ws);
  unsigned* c_cons = (unsigned*)(ws + 512);
  ull* h0_ring = (ull*)(ws + 4096);
  ull* h1_ring = (ull*)(ws + 4096 + (size_t)RINGN * HH * 8);

  // zero flags + rings every call: epochs restart at 0 (graph replay safe)
  hipMemsetAsync(ws, 0, 4096 + (size_t)2 * RINGN * HH * 8, stream);

  hipLaunchKernelGGL(deepar_persistent, dim3(NWG), dim3(512), 0, stream,
                     obs, Wih0, Whh0, b0, Wih1, Whh1, b1, Wdec, bdec, out,
                     b_cons, c_cons, h0_ring, h1_ring);
}

// Round 5
// 28449.677 us; speedup vs baseline: 5.4932x; 1.1320x over previous
//
#include <hip/hip_runtime.h>
#include <math.h>

#define TT 8192
#define DD 128
#define HH 1024
#define RINGN 64           // ring slots (power of 2); lag bound ~48 via amortized checks
#define NA 64              // layer-0 workgroups
#define NB 128             // layer-1 workgroups
#define NC 16              // decoder workgroups
#define NR 2               // relay workgroups (h0, h1)
#define NWG (NA + NB + NC + NR)

// d_ws layout (bytes):
//   [0)     b_cons u32[128]   B's consumption epoch of h0 (ring reuse)
//   [512)   c_cons u32[16]    C's consumption epoch of h1
//   [1024)  ready0 u32, 8 copies at stride 16 u32 (64B lines)
//   [2048)  ready1 u32, 8 copies
//   [4096)  h0_ring ull[RINGN][HH]   (value f32 | epoch u32) pairs
//   [4096 + RINGN*HH*8) h1_ring ull[RINGN][HH]
// Protocol: producers fire-and-forget 8B (value,epoch) pairs (relaxed agent
// atomics, no drains/fences). A relay WG per ring polls all 1024 pairs wide
// (it alone pays the wide spin), then publishes ready-epoch to 8 replicated
// lines. Consumers spin on ONE ready line (cheap, same-address coalesced),
// then bulk-read pairs once with an epoch-validate retry as a safety net.

typedef unsigned long long ull;

__device__ __forceinline__ ull ldpair(const ull* p) {
  return __hip_atomic_load(p, __ATOMIC_RELAXED, __HIP_MEMORY_SCOPE_AGENT);
}
__device__ __forceinline__ void stpair(ull* p, float v, unsigned e) {
  ull u = ((ull)e << 32) | (ull)__float_as_uint(v);
  __hip_atomic_store(p, u, __ATOMIC_RELAXED, __HIP_MEMORY_SCOPE_AGENT);
}
__device__ __forceinline__ unsigned ldflag(const unsigned* p) {
  return __hip_atomic_load(p, __ATOMIC_RELAXED, __HIP_MEMORY_SCOPE_AGENT);
}
__device__ __forceinline__ void stflag(unsigned* p, unsigned v) {
  __hip_atomic_store(p, v, __ATOMIC_RELAXED, __HIP_MEMORY_SCOPE_AGENT);
}
__device__ __forceinline__ float sigm(float x) { return 1.0f / (1.0f + expf(-x)); }
__device__ __forceinline__ float softplusf(float x) {
  return x > 0.0f ? x + log1pf(expf(-x)) : log1pf(expf(x));
}

#define FMA16(W)                                                      \
  a0 = fmaf(W[0][4*i+0], h4.x, a0); a0 = fmaf(W[0][4*i+1], h4.y, a0); \
  a0 = fmaf(W[0][4*i+2], h4.z, a0); a0 = fmaf(W[0][4*i+3], h4.w, a0); \
  a1 = fmaf(W[1][4*i+0], h4.x, a1); a1 = fmaf(W[1][4*i+1], h4.y, a1); \
  a1 = fmaf(W[1][4*i+2], h4.z, a1); a1 = fmaf(W[1][4*i+3], h4.w, a1); \
  a2 = fmaf(W[2][4*i+0], h4.x, a2); a2 = fmaf(W[2][4*i+1], h4.y, a2); \
  a2 = fmaf(W[2][4*i+2], h4.z, a2); a2 = fmaf(W[2][4*i+3], h4.w, a2); \
  a3 = fmaf(W[3][4*i+0], h4.x, a3); a3 = fmaf(W[3][4*i+1], h4.y, a3); \
  a3 = fmaf(W[3][4*i+2], h4.z, a3); a3 = fmaf(W[3][4*i+3], h4.w, a3);

__global__ void __launch_bounds__(512, 1) deepar_persistent(
    const float* __restrict__ obs,
    const float* __restrict__ Wih0, const float* __restrict__ Whh0, const float* __restrict__ b0,
    const float* __restrict__ Wih1, const float* __restrict__ Whh1, const float* __restrict__ b1,
    const float* __restrict__ Wdec, const float* __restrict__ bdec,
    float* __restrict__ out,
    unsigned* b_cons, unsigned* c_cons, unsigned* ready0, unsigned* ready1,
    ull* h0_ring, ull* h1_ring)
{
  __shared__ __align__(16) float hx[2][2304];   // double-buffered staged h

  const int wg  = blockIdx.x;
  const int tid = threadIdx.x;
  const int rc  = (wg & 7) * 16;                // ready-copy word index

  if (wg < NA) {
    //========== Group A: layer-0. 16 j's/WG; 32 lanes per j ==========
    const int rg = tid >> 5;          // 0..15 (j within WG)
    const int q  = tid & 31;          // 36-wide k-slice of [h0(1024); x(128)]
    const int j  = wg * 16 + rg;
    const int k0 = q * 36;
    float w[4][36];
    #pragma unroll
    for (int i = 0; i < 9; ++i) {
      const int kb = k0 + 4 * i;
      #pragma unroll
      for (int r = 0; r < 4; ++r) {
        const float* src = (kb < HH) ? (Whh0 + (size_t)(r * HH + j) * HH + kb)
                                     : (Wih0 + (size_t)(r * HH + j) * DD + (kb - HH));
        const float4 v = *(const float4*)src;
        w[r][4*i+0] = v.x; w[r][4*i+1] = v.y; w[r][4*i+2] = v.z; w[r][4*i+3] = v.w;
      }
    }
    float bs[4];
    #pragma unroll
    for (int r = 0; r < 4; ++r) bs[r] = b0[r * HH + j];
    float creg = 0.0f;

    for (int t = 0; t < TT; ++t) {
      float a0 = 0.f, a1 = 0.f, a2 = 0.f, a3 = 0.f;
      if (t > 0) {     // x-part: cached read-only loads, overlaps the wait
        const float* obr = obs + (size_t)(t - 1) * DD;
        #pragma unroll
        for (int i = 0; i < 9; ++i) {
          const int kb = k0 + 4 * i;
          if (kb >= HH) { const float4 h4 = *(const float4*)(obr + (kb - HH)); FMA16(w) }
        }
      }
      // amortized ring-reuse backpressure (wave0, every 16 steps)
      if (((t & 15) == 0) && t >= 48 && tid < 64) {
        const unsigned need = (unsigned)(t - 32);
        while (!__all((ldflag(&b_cons[tid]) >= need) &
                      (ldflag(&b_cons[tid + 64]) >= need))) {}
      }
      // cheap ready gate: one replicated counter line
      if (t > 0) while (ldflag(&ready0[rc]) < (unsigned)t) __builtin_amdgcn_s_sleep(1);
      // bulk-read h0(t-1) pairs once (validate-retry safety net) -> LDS
      float* Lb = hx[t & 1];
      {
        const ull* sl = h0_ring + (size_t)((t - 1) & (RINGN - 1)) * HH;
        const unsigned ee = (unsigned)t;
        bool d0 = false, d1 = false;
        do {
          ull u0 = 0, u1 = 0;
          if (!d0) u0 = ldpair(sl + tid);
          if (!d1) u1 = ldpair(sl + tid + 512);
          if (!d0 && (unsigned)(u0 >> 32) == ee) { Lb[tid]       = __uint_as_float((unsigned)u0); d0 = true; }
          if (!d1 && (unsigned)(u1 >> 32) == ee) { Lb[tid + 512] = __uint_as_float((unsigned)u1); d1 = true; }
        } while (!(d0 & d1));
      }
      __syncthreads();
      #pragma unroll
      for (int i = 0; i < 9; ++i) {
        const int kb = k0 + 4 * i;
        if (kb < HH) { const float4 h4 = *(const float4*)&Lb[kb]; FMA16(w) }
      }
      #pragma unroll
      for (int s = 1; s < 32; s <<= 1) {
        a0 += __shfl_xor(a0, s); a1 += __shfl_xor(a1, s);
        a2 += __shfl_xor(a2, s); a3 += __shfl_xor(a3, s);
      }
      if (q == 0) {
        const float ig = sigm(a0 + bs[0]);
        const float fg = sigm(a1 + bs[1]);
        const float gg = tanhf(a2 + bs[2]);
        const float og = sigm(a3 + bs[3]);
        creg = fg * creg + ig * gg;
        stpair(&h0_ring[(size_t)(t & (RINGN - 1)) * HH + j], og * tanhf(creg),
               (unsigned)(t + 1));
      }
    }

  } else if (wg < NA + NB) {
    //========== Group B: layer-1. 8 j's/WG; 64 lanes per j ==========
    const int rg = tid >> 6;          // 0..7
    const int q  = tid & 63;          // 32-wide k-slice of [h0(t); h1(t-1)]
    const int s_ = wg - NA;
    const int j  = s_ * 8 + rg;
    const int k0 = q * 32;
    float w[4][32];
    #pragma unroll
    for (int i = 0; i < 8; ++i) {
      const int kb = k0 + 4 * i;
      #pragma unroll
      for (int r = 0; r < 4; ++r) {
        const float* src = (kb < HH) ? (Wih1 + (size_t)(r * HH + j) * HH + kb)
                                     : (Whh1 + (size_t)(r * HH + j) * HH + (kb - HH));
        const float4 v = *(const float4*)src;
        w[r][4*i+0] = v.x; w[r][4*i+1] = v.y; w[r][4*i+2] = v.z; w[r][4*i+3] = v.w;
      }
    }
    float bs[4];
    #pragma unroll
    for (int r = 0; r < 4; ++r) bs[r] = b1[r * HH + j];
    float creg = 0.0f;
    const int p0 = tid + 4 * (tid >> 5);      // padded: e + 4*(e>>5)
    const int p1 = p0 + 576;
    const int p2 = p0 + 1152;
    const int p3 = p2 + 576;

    for (int t = 0; t < TT; ++t) {
      if (((t & 15) == 0) && t >= 48 && tid < 64) {    // C's h1 consumption
        const unsigned need = (unsigned)(t - 32);
        while (!__all((tid >= NC) | (ldflag(&c_cons[tid]) >= need))) {}
      }
      while (ldflag(&ready0[rc]) < (unsigned)(t + 1)) __builtin_amdgcn_s_sleep(1);
      if (t > 0)
        while (ldflag(&ready1[rc]) < (unsigned)t) __builtin_amdgcn_s_sleep(1);
      float* Lb = hx[t & 1];
      {
        const ull* s0 = h0_ring + (size_t)(t & (RINGN - 1)) * HH;
        const ull* s1 = h1_ring + (size_t)((t - 1) & (RINGN - 1)) * HH;
        const unsigned e0 = (unsigned)(t + 1);
        const unsigned e1 = (unsigned)t;
        bool d0 = false, d1 = false, d2 = false, d3 = false;
        do {
          ull u0 = 0, u1 = 0, u2 = 0, u3 = 0;
          if (!d0) u0 = ldpair(s0 + tid);
          if (!d1) u1 = ldpair(s0 + tid + 512);
          if (!d2) u2 = ldpair(s1 + tid);
          if (!d3) u3 = ldpair(s1 + tid + 512);
          if (!d0 && (unsigned)(u0 >> 32) == e0) { Lb[p0] = __uint_as_float((unsigned)u0); d0 = true; }
          if (!d1 && (unsigned)(u1 >> 32) == e0) { Lb[p1] = __uint_as_float((unsigned)u1); d1 = true; }
          if (!d2 && (unsigned)(u2 >> 32) == e1) { Lb[p2] = __uint_as_float((unsigned)u2); d2 = true; }
          if (!d3 && (unsigned)(u3 >> 32) == e1) { Lb[p3] = __uint_as_float((unsigned)u3); d3 = true; }
        } while (!(d0 & d1 & d2 & d3));
      }
      __syncthreads();
      if (tid == 0) stflag(&b_cons[s_], (unsigned)(t + 1));  // h0(t) consumed
      float a0 = 0.f, a1 = 0.f, a2 = 0.f, a3 = 0.f;
      {
        const int base = q * 36;
        #pragma unroll
        for (int i = 0; i < 8; ++i) {
          const float4 h4 = *(const float4*)&Lb[base + 4 * i];
          FMA16(w)
        }
      }
      #pragma unroll
      for (int s = 1; s < 64; s <<= 1) {
        a0 += __shfl_xor(a0, s); a1 += __shfl_xor(a1, s);
        a2 += __shfl_xor(a2, s); a3 += __shfl_xor(a3, s);
      }
      if (q == 0) {
        const float ig = sigm(a0 + bs[0]);
        const float fg = sigm(a1 + bs[1]);
        const float gg = tanhf(a2 + bs[2]);
        const float og = sigm(a3 + bs[3]);
        creg = fg * creg + ig * gg;
        stpair(&h1_ring[(size_t)(t & (RINGN - 1)) * HH + j], og * tanhf(creg),
               (unsigned)(t + 1));
      }
    }

  } else if (wg < NA + NB + NC) {
    //========== Group C: decoder. 16 rows/WG; 2 rows per 64-lane group ==========
    const int rg = tid >> 6;
    const int q  = tid & 63;
    const int cg = wg - NA - NB;
    const int row0 = cg * 16 + 2 * rg;
    const int k0 = q * 16;
    float w[2][16];
    #pragma unroll
    for (int i = 0; i < 4; ++i) {
      const int kb = k0 + 4 * i;
      #pragma unroll
      for (int r = 0; r < 2; ++r) {
        const float4 v = *(const float4*)(Wdec + (size_t)(row0 + r) * HH + kb);
        w[r][4*i+0] = v.x; w[r][4*i+1] = v.y; w[r][4*i+2] = v.z; w[r][4*i+3] = v.w;
      }
    }
    const float bs0 = bdec[row0], bs1 = bdec[row0 + 1];
    const int pc0 = tid + 4 * (tid >> 4);     // padded: e + 4*(e>>4)
    const int pc1 = pc0 + 640;

    for (int t = 0; t < TT; ++t) {
      while (ldflag(&ready1[rc]) < (unsigned)(t + 1)) __builtin_amdgcn_s_sleep(1);
      float* Lb = hx[t & 1];
      {
        const ull* sl = h1_ring + (size_t)(t & (RINGN - 1)) * HH;
        const unsigned ee = (unsigned)(t + 1);
        bool d0 = false, d1 = false;
        do {
          ull u0 = 0, u1 = 0;
          if (!d0) u0 = ldpair(sl + tid);
          if (!d1) u1 = ldpair(sl + tid + 512);
          if (!d0 && (unsigned)(u0 >> 32) == ee) { Lb[pc0] = __uint_as_float((unsigned)u0); d0 = true; }
          if (!d1 && (unsigned)(u1 >> 32) == ee) { Lb[pc1] = __uint_as_float((unsigned)u1); d1 = true; }
        } while (!(d0 & d1));
      }
      __syncthreads();
      if (tid == 0) stflag(&c_cons[cg], (unsigned)(t + 1));  // h1(t) consumed
      float a0 = 0.f, a1 = 0.f;
      {
        const int base = q * 20;
        #pragma unroll
        for (int i = 0; i < 4; ++i) {
          const float4 h4 = *(const float4*)&Lb[base + 4 * i];
          a0 = fmaf(w[0][4*i+0], h4.x, a0); a0 = fmaf(w[0][4*i+1], h4.y, a0);
          a0 = fmaf(w[0][4*i+2], h4.z, a0); a0 = fmaf(w[0][4*i+3], h4.w, a0);
          a1 = fmaf(w[1][4*i+0], h4.x, a1); a1 = fmaf(w[1][4*i+1], h4.y, a1);
          a1 = fmaf(w[1][4*i+2], h4.z, a1); a1 = fmaf(w[1][4*i+3], h4.w, a1);
        }
      }
      #pragma unroll
      for (int s = 1; s < 64; s <<= 1) { a0 += __shfl_xor(a0, s); a1 += __shfl_xor(a1, s); }
      if (q == 0) {
        const float z0 = a0 + bs0;
        const float z1 = a1 + bs1;
        if (row0 < DD) {
          out[(size_t)t * DD + row0]     = z0;
          out[(size_t)t * DD + row0 + 1] = z1;
        } else {
          out[(size_t)TT * DD + (size_t)t * DD + (row0 - DD)]     = softplusf(z0) + 1e-4f;
          out[(size_t)TT * DD + (size_t)t * DD + (row0 - DD) + 1] = softplusf(z1) + 1e-4f;
        }
      }
    }

  } else {
    //========== Relay WGs: wide-poll one ring, publish ready epochs ==========
    ull* ring      = (wg == NA + NB + NC) ? h0_ring : h1_ring;
    unsigned* rdy  = (wg == NA + NB + NC) ? ready0  : ready1;
    for (int t = 0; t < TT; ++t) {
      const ull* sl = ring + (size_t)(t & (RINGN - 1)) * HH;
      const unsigned ee = (unsigned)(t + 1);
      bool d0 = false, d1 = false;
      do {
        ull u0 = 0, u1 = 0;
        if (!d0) u0 = ldpair(sl + tid);
        if (!d1) u1 = ldpair(sl + tid + 512);
        d0 = d0 || ((unsigned)(u0 >> 32) == ee);
        d1 = d1 || ((unsigned)(u1 >> 32) == ee);
      } while (!(d0 & d1));
      __syncthreads();                 // all 1024 pairs confirmed at coherence pt
      if (tid < 8) {
        asm volatile("" ::: "memory"); // keep flag store after the loads
        stflag(&rdy[tid * 16], ee);    // 8 replicated copies, one line each
      }
    }
  }
}

extern "C" void kernel_launch(void* const* d_in, const int* in_sizes, int n_in,
                              void* d_out, int out_size, void* d_ws, size_t ws_size,
                              hipStream_t stream) {
  const float* obs  = (const float*)d_in[0];
  const float* Wih0 = (const float*)d_in[1];
  const float* Whh0 = (const float*)d_in[2];
  const float* b0   = (const float*)d_in[3];
  const float* Wih1 = (const float*)d_in[4];
  const float* Whh1 = (const float*)d_in[5];
  const float* b1   = (const float*)d_in[6];
  const float* Wdec = (const float*)d_in[7];
  const float* bdec = (const float*)d_in[8];
  float* out = (float*)d_out;

  unsigned char* ws = (unsigned char*)d_ws;
  unsigned* b_cons = (unsigned*)(ws);
  unsigned* c_cons = (unsigned*)(ws + 512);
  unsigned* ready0 = (unsigned*)(ws + 1024);
  unsigned* ready1 = (unsigned*)(ws + 2048);
  ull* h0_ring = (ull*)(ws + 4096);
  ull* h1_ring = (ull*)(ws + 4096 + (size_t)RINGN * HH * 8);

  // zero flags + rings every call: epochs restart at 0 (graph replay safe)
  hipMemsetAsync(ws, 0, 4096 + (size_t)2 * RINGN * HH * 8, stream);

  hipLaunchKernelGGL(deepar_persistent, dim3(NWG), dim3(512), 0, stream,
                     obs, Wih0, Whh0, b0, Wih1, Whh1, b1, Wdec, bdec, out,
                     b_cons, c_cons, ready0, ready1, h0_ring, h1_ring);
}